// Round 5
// baseline (44.462 us; speedup 1.0000x reference)
//
#include <hip/hip_runtime.h>
#include <math.h>
#include <stdint.h>

#define DEG 16
#define FDIM 128
#define EPSV 1e-12f

__device__ __forceinline__ uint32_t f32_to_bf16_rne(float f) {
    uint32_t u = __float_as_uint(f);
    return (u + 0x7fffu + ((u >> 16) & 1u)) >> 16;
}

__device__ __forceinline__ void unpack8(const uint4 u, float* f) {
    f[0] = __uint_as_float(u.x << 16); f[1] = __uint_as_float(u.x & 0xffff0000u);
    f[2] = __uint_as_float(u.y << 16); f[3] = __uint_as_float(u.y & 0xffff0000u);
    f[4] = __uint_as_float(u.z << 16); f[5] = __uint_as_float(u.z & 0xffff0000u);
    f[6] = __uint_as_float(u.w << 16); f[7] = __uint_as_float(u.w & 0xffff0000u);
}

__device__ __forceinline__ float dot8(const float* xi, const uint4 u) {
    float xv[8];
    unpack8(u, xv);
    float d0 = xi[0] * xv[0];
    float d1 = xi[1] * xv[1];
#pragma unroll
    for (int q = 2; q < 8; q += 2) {
        d0 = fmaf(xi[q],     xv[q],     d0);
        d1 = fmaf(xi[q + 1], xv[q + 1], d1);
    }
    return d0 + d1;
}

// Prep: one wave per row. rsqrt(|x|^2+eps) from fp32 AND packed-bf16 copy.
__global__ void agnn_prep_kernel(const float* __restrict__ x,
                                 uint32_t* __restrict__ xbf,
                                 float* __restrict__ rn, int n) {
    int wave = (blockIdx.x * blockDim.x + threadIdx.x) >> 6;
    int lane = threadIdx.x & 63;
    if (wave >= n) return;
    const float2 v = *reinterpret_cast<const float2*>(x + (size_t)wave * FDIM + lane * 2);
    float s = v.x * v.x + v.y * v.y;
#pragma unroll
    for (int off = 32; off >= 1; off >>= 1)
        s += __shfl_xor(s, off);
    if (lane == 0) rn[wave] = rsqrtf(s + EPSV);
    xbf[(size_t)wave * (FDIM / 2) + lane] =
        f32_to_bf16_rne(v.x) | (f32_to_bf16_rne(v.y) << 16);
}

// Main v5: TWO nodes per wave (independent chains interleaved for latency
// hiding), 4 groups x 16 lanes per node; group g owns neighbors 4g..4g+3,
// lane t owns 16B chunk t. Neighbor rows kept PACKED (unpacked on the fly
// twice - proven free in round 4) to control VGPR. Softmax max-subtraction
// dropped: |e| <= |beta| so exp(e) is stable; identical result.
__global__ __launch_bounds__(256, 4)
void agnn_main_v5(const uint32_t* __restrict__ xbf,
                  const int* __restrict__ col_id,
                  const float* __restrict__ rn,
                  const float* __restrict__ beta,
                  float* __restrict__ out, int n) {
    int wid  = (blockIdx.x * blockDim.x + threadIdx.x) >> 6;
    int lane = threadIdx.x & 63;
    const int nA = 2 * wid;
    if (nA >= n) return;
    const int nB = (nA + 1 < n) ? (nA + 1) : nA;
    const int g = lane >> 4;       // group 0..3 -> neighbors 4g..4g+3
    const int t = lane & 15;       // 16B chunk index within row

    // ---- issue ALL independent loads up front (both nodes) ----
    const int4  cA = *reinterpret_cast<const int4*>(col_id + nA * DEG + 4 * g);
    const int4  cB = *reinterpret_cast<const int4*>(col_id + nB * DEG + 4 * g);
    const uint4 xiuA = *reinterpret_cast<const uint4*>(xbf + (size_t)nA * (FDIM / 2) + t * 4);
    const uint4 xiuB = *reinterpret_cast<const uint4*>(xbf + (size_t)nB * (FDIM / 2) + t * 4);
    const float b    = beta[0];
    const float rniA = rn[nA];
    const float rniB = rn[nB];

    uint4 a0 = *reinterpret_cast<const uint4*>(xbf + (size_t)cA.x * (FDIM / 2) + t * 4);
    uint4 a1 = *reinterpret_cast<const uint4*>(xbf + (size_t)cA.y * (FDIM / 2) + t * 4);
    uint4 a2 = *reinterpret_cast<const uint4*>(xbf + (size_t)cA.z * (FDIM / 2) + t * 4);
    uint4 a3 = *reinterpret_cast<const uint4*>(xbf + (size_t)cA.w * (FDIM / 2) + t * 4);
    uint4 b0 = *reinterpret_cast<const uint4*>(xbf + (size_t)cB.x * (FDIM / 2) + t * 4);
    uint4 b1 = *reinterpret_cast<const uint4*>(xbf + (size_t)cB.y * (FDIM / 2) + t * 4);
    uint4 b2 = *reinterpret_cast<const uint4*>(xbf + (size_t)cB.z * (FDIM / 2) + t * 4);
    uint4 b3 = *reinterpret_cast<const uint4*>(xbf + (size_t)cB.w * (FDIM / 2) + t * 4);

    float rnjA0 = rn[cA.x], rnjA1 = rn[cA.y], rnjA2 = rn[cA.z], rnjA3 = rn[cA.w];
    float rnjB0 = rn[cB.x], rnjB1 = rn[cB.y], rnjB2 = rn[cB.z], rnjB3 = rn[cB.w];

    float xiA[8], xiB[8];
    unpack8(xiuA, xiA);
    unpack8(xiuB, xiB);

    // per-lane partial dots (packed rows unpacked transiently)
    float pA[4], pB[4];
    pA[0] = dot8(xiA, a0); pB[0] = dot8(xiB, b0);
    pA[1] = dot8(xiA, a1); pB[1] = dot8(xiB, b1);
    pA[2] = dot8(xiA, a2); pB[2] = dot8(xiB, b2);
    pA[3] = dot8(xiA, a3); pB[3] = dot8(xiB, b3);

    // intra-group (16-lane) joint butterfly: 4 steps x 8 independent values
#pragma unroll
    for (int off = 1; off < 16; off <<= 1) {
#pragma unroll
        for (int r = 0; r < 4; ++r) {
            pA[r] += __shfl_xor(pA[r], off);
            pB[r] += __shfl_xor(pB[r], off);
        }
    }

    // scale + exp (no max subtraction: |e| <= |beta|, stable)
    const float bA = b * rniA, bB = b * rniB;
    pA[0] = __expf(pA[0] * (bA * rnjA0));
    pA[1] = __expf(pA[1] * (bA * rnjA1));
    pA[2] = __expf(pA[2] * (bA * rnjA2));
    pA[3] = __expf(pA[3] * (bA * rnjA3));
    pB[0] = __expf(pB[0] * (bB * rnjB0));
    pB[1] = __expf(pB[1] * (bB * rnjB1));
    pB[2] = __expf(pB[2] * (bB * rnjB2));
    pB[3] = __expf(pB[3] * (bB * rnjB3));

    float sA = (pA[0] + pA[1]) + (pA[2] + pA[3]);
    float sB = (pB[0] + pB[1]) + (pB[2] + pB[3]);
    sA += __shfl_xor(sA, 16);  sB += __shfl_xor(sB, 16);
    sA += __shfl_xor(sA, 32);  sB += __shfl_xor(sB, 32);
    const float invA = 1.0f / sA;
    const float invB = 1.0f / sB;

    // aggregation (second transient unpack of the packed rows)
    float accA[8], accB[8];
    {
        float xv[8], w;
        unpack8(a0, xv); w = pA[0] * invA;
#pragma unroll
        for (int q = 0; q < 8; ++q) accA[q] = w * xv[q];
        unpack8(a1, xv); w = pA[1] * invA;
#pragma unroll
        for (int q = 0; q < 8; ++q) accA[q] = fmaf(w, xv[q], accA[q]);
        unpack8(a2, xv); w = pA[2] * invA;
#pragma unroll
        for (int q = 0; q < 8; ++q) accA[q] = fmaf(w, xv[q], accA[q]);
        unpack8(a3, xv); w = pA[3] * invA;
#pragma unroll
        for (int q = 0; q < 8; ++q) accA[q] = fmaf(w, xv[q], accA[q]);

        unpack8(b0, xv); w = pB[0] * invB;
#pragma unroll
        for (int q = 0; q < 8; ++q) accB[q] = w * xv[q];
        unpack8(b1, xv); w = pB[1] * invB;
#pragma unroll
        for (int q = 0; q < 8; ++q) accB[q] = fmaf(w, xv[q], accB[q]);
        unpack8(b2, xv); w = pB[2] * invB;
#pragma unroll
        for (int q = 0; q < 8; ++q) accB[q] = fmaf(w, xv[q], accB[q]);
        unpack8(b3, xv); w = pB[3] * invB;
#pragma unroll
        for (int q = 0; q < 8; ++q) accB[q] = fmaf(w, xv[q], accB[q]);
    }

    // cross-group reduce: 2 steps x 16 independent values
#pragma unroll
    for (int q = 0; q < 8; ++q) { accA[q] += __shfl_xor(accA[q], 16); accB[q] += __shfl_xor(accB[q], 16); }
#pragma unroll
    for (int q = 0; q < 8; ++q) { accA[q] += __shfl_xor(accA[q], 32); accB[q] += __shfl_xor(accB[q], 32); }

    if (g == 0) {
        float4* opA = reinterpret_cast<float4*>(out + (size_t)nA * FDIM + t * 8);
        opA[0] = make_float4(accA[0], accA[1], accA[2], accA[3]);
        opA[1] = make_float4(accA[4], accA[5], accA[6], accA[7]);
        float4* opB = reinterpret_cast<float4*>(out + (size_t)nB * FDIM + t * 8);
        opB[0] = make_float4(accB[0], accB[1], accB[2], accB[3]);
        opB[1] = make_float4(accB[4], accB[5], accB[6], accB[7]);
    }
}

// ---------- fp32 fallback (only if ws too small for the bf16 copy) ----------
__global__ void agnn_rnorm_kernel(const float* __restrict__ x,
                                  float* __restrict__ rn, int n) {
    int wave = (blockIdx.x * blockDim.x + threadIdx.x) >> 6;
    int lane = threadIdx.x & 63;
    if (wave >= n) return;
    const float2 v = *reinterpret_cast<const float2*>(x + (size_t)wave * FDIM + lane * 2);
    float s = v.x * v.x + v.y * v.y;
#pragma unroll
    for (int off = 32; off >= 1; off >>= 1)
        s += __shfl_xor(s, off);
    if (lane == 0) rn[wave] = rsqrtf(s + EPSV);
}

__global__ void agnn_main_f32(const float* __restrict__ x,
                              const int* __restrict__ col_id,
                              const float* __restrict__ rn,
                              const float* __restrict__ beta,
                              float* __restrict__ out, int n) {
    int wave = (blockIdx.x * blockDim.x + threadIdx.x) >> 6;
    int lane = threadIdx.x & 63;
    if (wave >= n) return;
    const int node = wave;
    const float b   = beta[0];
    const float rni = rn[node];
    const float2 xi = *reinterpret_cast<const float2*>(x + (size_t)node * FDIM + lane * 2);
    int cidx = col_id[node * DEG + (lane & 15)];
    float2 xj[DEG];
    float  p[DEG];
    float  rnj[DEG];
#pragma unroll
    for (int k = 0; k < DEG; ++k) {
        int cj = __shfl(cidx, k);
        const float2 v = *reinterpret_cast<const float2*>(x + (size_t)cj * FDIM + lane * 2);
        xj[k] = v; rnj[k] = rn[cj];
        p[k] = fmaf(xi.x, v.x, xi.y * v.y);
    }
#pragma unroll
    for (int off = 32; off >= 1; off >>= 1) {
#pragma unroll
        for (int k = 0; k < DEG; ++k)
            p[k] += __shfl_xor(p[k], off);
    }
    const float brni = b * rni;
#pragma unroll
    for (int k = 0; k < DEG; ++k) p[k] *= brni * rnj[k];
    float m = p[0];
#pragma unroll
    for (int k = 1; k < DEG; ++k) m = fmaxf(m, p[k]);
    float s = 0.f;
#pragma unroll
    for (int k = 0; k < DEG; ++k) { p[k] = __expf(p[k] - m); s += p[k]; }
    const float inv = 1.0f / s;
    float2 acc = make_float2(0.f, 0.f);
#pragma unroll
    for (int k = 0; k < DEG; ++k) {
        const float a = p[k] * inv;
        acc.x = fmaf(a, xj[k].x, acc.x);
        acc.y = fmaf(a, xj[k].y, acc.y);
    }
    *reinterpret_cast<float2*>(out + (size_t)node * FDIM + lane * 2) = acc;
}

extern "C" void kernel_launch(void* const* d_in, const int* in_sizes, int n_in,
                              void* d_out, int out_size, void* d_ws, size_t ws_size,
                              hipStream_t stream) {
    const float* x      = (const float*)d_in[0];
    const int*   col_id = (const int*)d_in[3];
    const float* beta   = (const float*)d_in[4];
    float*       out    = (float*)d_out;

    const int n = in_sizes[0] / FDIM;            // 50000

    const int block = 256;                       // 4 waves / block
    const int wavesPerBlock = block / 64;
    const int gridPrep = (n + wavesPerBlock - 1) / wavesPerBlock;

    const size_t xbf_bytes = (size_t)n * (FDIM / 2) * sizeof(uint32_t);  // 12.8 MB
    const size_t need = xbf_bytes + (size_t)n * sizeof(float);

    if (ws_size >= need) {
        uint32_t* xbf = (uint32_t*)d_ws;
        float*    rn  = (float*)((char*)d_ws + xbf_bytes);
        const int nPairs   = (n + 1) / 2;        // 2 nodes per wave
        const int gridMain = (nPairs + wavesPerBlock - 1) / wavesPerBlock;
        agnn_prep_kernel<<<gridPrep, block, 0, stream>>>(x, xbf, rn, n);
        agnn_main_v5<<<gridMain, block, 0, stream>>>(xbf, col_id, rn, beta, out, n);
    } else {
        float* rn = (float*)d_ws;
        agnn_rnorm_kernel<<<gridPrep, block, 0, stream>>>(x, rn, n);
        agnn_main_f32<<<gridPrep, block, 0, stream>>>(x, col_id, rn, beta, out, n);
    }
}

// Round 6
// 42.591 us; speedup vs baseline: 1.0439x; 1.0439x over previous
//
#include <hip/hip_runtime.h>
#include <math.h>
#include <stdint.h>

#define DEG 16
#define FDIM 128
#define EPSV 1e-12f

typedef _Float16 h2 __attribute__((ext_vector_type(2)));

__device__ __forceinline__ h2 bc_h2(uint32_t u) { h2 h; __builtin_memcpy(&h, &u, 4); return h; }
__device__ __forceinline__ uint32_t bc_u32(h2 h) { uint32_t u; __builtin_memcpy(&u, &h, 4); return u; }

#if __has_builtin(__builtin_amdgcn_fdot2)
#define FDOT2(a, b, c) __builtin_amdgcn_fdot2((a), (b), (c), false)
#else
__device__ __forceinline__ float FDOT2(h2 a, h2 b, float c) {
    return c + (float)a[0] * (float)b[0] + (float)a[1] * (float)b[1];
}
#endif

// dot of two packed-f16 8-element chunks, f32 accumulate (v_dot2_f32_f16 x4)
__device__ __forceinline__ float dot8h(uint4 a, uint4 x) {
    float d0 = FDOT2(bc_h2(a.x), bc_h2(x.x), 0.f);
    float d1 = FDOT2(bc_h2(a.y), bc_h2(x.y), 0.f);
    d0 = FDOT2(bc_h2(a.z), bc_h2(x.z), d0);
    d1 = FDOT2(bc_h2(a.w), bc_h2(x.w), d1);
    return d0 + d1;
}

// Prep: one wave per row. rsqrt(|x|^2+eps) from fp32 AND packed-f16 copy.
__global__ void agnn_prep_f16(const float* __restrict__ x,
                              uint32_t* __restrict__ xh,
                              float* __restrict__ rn, int n) {
    int wave = (blockIdx.x * blockDim.x + threadIdx.x) >> 6;
    int lane = threadIdx.x & 63;
    if (wave >= n) return;
    const float2 v = *reinterpret_cast<const float2*>(x + (size_t)wave * FDIM + lane * 2);
    float s = v.x * v.x + v.y * v.y;
#pragma unroll
    for (int off = 32; off >= 1; off >>= 1)
        s += __shfl_xor(s, off);
    if (lane == 0) rn[wave] = rsqrtf(s + EPSV);
    h2 hv = { (_Float16)v.x, (_Float16)v.y };   // RNE
    xh[(size_t)wave * (FDIM / 2) + lane] = bc_u32(hv);
}

// Main v6: one wave per node, 4 groups x 16 lanes; group g owns neighbors
// 4g..4g+3, lane t owns the 16B packed-f16 chunk t. Rows stay PACKED:
// dot via v_dot2_f32_f16, aggregation via v_pk_fma_f16. No unpacking.
// No softmax max-subtraction (|e| <= |beta|; validated in round 5).
__global__ __launch_bounds__(256, 8)
void agnn_main_v6(const uint32_t* __restrict__ xh,
                  const int* __restrict__ col_id,
                  const float* __restrict__ rn,
                  const float* __restrict__ beta,
                  float* __restrict__ out, int n) {
    int node = (blockIdx.x * blockDim.x + threadIdx.x) >> 6;
    int lane = threadIdx.x & 63;
    if (node >= n) return;
    const int g = lane >> 4;       // group -> neighbors 4g..4g+3
    const int t = lane & 15;       // 16B chunk index within row

    // issue all independent loads up front
    const int4  c4  = *reinterpret_cast<const int4*>(col_id + node * DEG + 4 * g);
    const uint4 xiu = *reinterpret_cast<const uint4*>(xh + (size_t)node * (FDIM / 2) + t * 4);
    const float b   = beta[0];
    const float rni = rn[node];

    const uint4 a0 = *reinterpret_cast<const uint4*>(xh + (size_t)c4.x * (FDIM / 2) + t * 4);
    const uint4 a1 = *reinterpret_cast<const uint4*>(xh + (size_t)c4.y * (FDIM / 2) + t * 4);
    const uint4 a2 = *reinterpret_cast<const uint4*>(xh + (size_t)c4.z * (FDIM / 2) + t * 4);
    const uint4 a3 = *reinterpret_cast<const uint4*>(xh + (size_t)c4.w * (FDIM / 2) + t * 4);
    const float rnj0 = rn[c4.x], rnj1 = rn[c4.y], rnj2 = rn[c4.z], rnj3 = rn[c4.w];

    // per-lane partial dots on packed data
    float p[4];
    p[0] = dot8h(a0, xiu);
    p[1] = dot8h(a1, xiu);
    p[2] = dot8h(a2, xiu);
    p[3] = dot8h(a3, xiu);

    // intra-group (16-lane) joint butterfly: 4 steps x 4 values
#pragma unroll
    for (int off = 1; off < 16; off <<= 1) {
#pragma unroll
        for (int r = 0; r < 4; ++r)
            p[r] += __shfl_xor(p[r], off);
    }

    // scale + exp (no max subtraction: |e| <= |beta|)
    const float brni = b * rni;
    p[0] = __expf(p[0] * (brni * rnj0));
    p[1] = __expf(p[1] * (brni * rnj1));
    p[2] = __expf(p[2] * (brni * rnj2));
    p[3] = __expf(p[3] * (brni * rnj3));

    float s = (p[0] + p[1]) + (p[2] + p[3]);
    s += __shfl_xor(s, 16);
    s += __shfl_xor(s, 32);
    const float inv = 1.0f / s;

    // aggregation fully packed: acc[q] (h2) += w_r * row_r.chunk[q]
    h2 acc0 = (h2)0, acc1 = (h2)0, acc2 = (h2)0, acc3 = (h2)0;
    {
        _Float16 w;
        h2 wv;
        w = (_Float16)(p[0] * inv); wv = (h2){w, w};
        acc0 = __builtin_elementwise_fma(wv, bc_h2(a0.x), acc0);
        acc1 = __builtin_elementwise_fma(wv, bc_h2(a0.y), acc1);
        acc2 = __builtin_elementwise_fma(wv, bc_h2(a0.z), acc2);
        acc3 = __builtin_elementwise_fma(wv, bc_h2(a0.w), acc3);
        w = (_Float16)(p[1] * inv); wv = (h2){w, w};
        acc0 = __builtin_elementwise_fma(wv, bc_h2(a1.x), acc0);
        acc1 = __builtin_elementwise_fma(wv, bc_h2(a1.y), acc1);
        acc2 = __builtin_elementwise_fma(wv, bc_h2(a1.z), acc2);
        acc3 = __builtin_elementwise_fma(wv, bc_h2(a1.w), acc3);
        w = (_Float16)(p[2] * inv); wv = (h2){w, w};
        acc0 = __builtin_elementwise_fma(wv, bc_h2(a2.x), acc0);
        acc1 = __builtin_elementwise_fma(wv, bc_h2(a2.y), acc1);
        acc2 = __builtin_elementwise_fma(wv, bc_h2(a2.z), acc2);
        acc3 = __builtin_elementwise_fma(wv, bc_h2(a2.w), acc3);
        w = (_Float16)(p[3] * inv); wv = (h2){w, w};
        acc0 = __builtin_elementwise_fma(wv, bc_h2(a3.x), acc0);
        acc1 = __builtin_elementwise_fma(wv, bc_h2(a3.y), acc1);
        acc2 = __builtin_elementwise_fma(wv, bc_h2(a3.z), acc2);
        acc3 = __builtin_elementwise_fma(wv, bc_h2(a3.w), acc3);
    }

    // cross-group reduce on packed u32: 2 steps x 4 values (v_pk_add_f16)
#pragma unroll
    for (int off = 16; off <= 32; off <<= 1) {
        acc0 += bc_h2((uint32_t)__shfl_xor((int)bc_u32(acc0), off));
        acc1 += bc_h2((uint32_t)__shfl_xor((int)bc_u32(acc1), off));
        acc2 += bc_h2((uint32_t)__shfl_xor((int)bc_u32(acc2), off));
        acc3 += bc_h2((uint32_t)__shfl_xor((int)bc_u32(acc3), off));
    }

    if (g == 0) {
        float4* op = reinterpret_cast<float4*>(out + (size_t)node * FDIM + t * 8);
        op[0] = make_float4((float)acc0[0], (float)acc0[1], (float)acc1[0], (float)acc1[1]);
        op[1] = make_float4((float)acc2[0], (float)acc2[1], (float)acc3[0], (float)acc3[1]);
    }
}

// ---------- fp32 fallback (only if ws too small for the f16 copy) ----------
__global__ void agnn_rnorm_kernel(const float* __restrict__ x,
                                  float* __restrict__ rn, int n) {
    int wave = (blockIdx.x * blockDim.x + threadIdx.x) >> 6;
    int lane = threadIdx.x & 63;
    if (wave >= n) return;
    const float2 v = *reinterpret_cast<const float2*>(x + (size_t)wave * FDIM + lane * 2);
    float s = v.x * v.x + v.y * v.y;
#pragma unroll
    for (int off = 32; off >= 1; off >>= 1)
        s += __shfl_xor(s, off);
    if (lane == 0) rn[wave] = rsqrtf(s + EPSV);
}

__global__ void agnn_main_f32(const float* __restrict__ x,
                              const int* __restrict__ col_id,
                              const float* __restrict__ rn,
                              const float* __restrict__ beta,
                              float* __restrict__ out, int n) {
    int wave = (blockIdx.x * blockDim.x + threadIdx.x) >> 6;
    int lane = threadIdx.x & 63;
    if (wave >= n) return;
    const int node = wave;
    const float b   = beta[0];
    const float rni = rn[node];
    const float2 xi = *reinterpret_cast<const float2*>(x + (size_t)node * FDIM + lane * 2);
    int cidx = col_id[node * DEG + (lane & 15)];
    float2 xj[DEG];
    float  p[DEG];
    float  rnj[DEG];
#pragma unroll
    for (int k = 0; k < DEG; ++k) {
        int cj = __shfl(cidx, k);
        const float2 v = *reinterpret_cast<const float2*>(x + (size_t)cj * FDIM + lane * 2);
        xj[k] = v; rnj[k] = rn[cj];
        p[k] = fmaf(xi.x, v.x, xi.y * v.y);
    }
#pragma unroll
    for (int off = 32; off >= 1; off >>= 1) {
#pragma unroll
        for (int k = 0; k < DEG; ++k)
            p[k] += __shfl_xor(p[k], off);
    }
    const float brni = b * rni;
#pragma unroll
    for (int k = 0; k < DEG; ++k) p[k] *= brni * rnj[k];
    float m = p[0];
#pragma unroll
    for (int k = 1; k < DEG; ++k) m = fmaxf(m, p[k]);
    float s = 0.f;
#pragma unroll
    for (int k = 0; k < DEG; ++k) { p[k] = __expf(p[k] - m); s += p[k]; }
    const float inv = 1.0f / s;
    float2 acc = make_float2(0.f, 0.f);
#pragma unroll
    for (int k = 0; k < DEG; ++k) {
        const float a = p[k] * inv;
        acc.x = fmaf(a, xj[k].x, acc.x);
        acc.y = fmaf(a, xj[k].y, acc.y);
    }
    *reinterpret_cast<float2*>(out + (size_t)node * FDIM + lane * 2) = acc;
}

extern "C" void kernel_launch(void* const* d_in, const int* in_sizes, int n_in,
                              void* d_out, int out_size, void* d_ws, size_t ws_size,
                              hipStream_t stream) {
    const float* x      = (const float*)d_in[0];
    const int*   col_id = (const int*)d_in[3];
    const float* beta   = (const float*)d_in[4];
    float*       out    = (float*)d_out;

    const int n = in_sizes[0] / FDIM;            // 50000

    const int block = 256;                       // 4 waves / block
    const int wavesPerBlock = block / 64;
    const int grid = (n + wavesPerBlock - 1) / wavesPerBlock;

    const size_t xh_bytes = (size_t)n * (FDIM / 2) * sizeof(uint32_t);  // 12.8 MB
    const size_t need = xh_bytes + (size_t)n * sizeof(float);

    if (ws_size >= need) {
        uint32_t* xh = (uint32_t*)d_ws;
        float*    rn = (float*)((char*)d_ws + xh_bytes);
        agnn_prep_f16<<<grid, block, 0, stream>>>(x, xh, rn, n);
        agnn_main_v6<<<grid, block, 0, stream>>>(xh, col_id, rn, beta, out, n);
    } else {
        float* rn = (float*)d_ws;
        agnn_rnorm_kernel<<<grid, block, 0, stream>>>(x, rn, n);
        agnn_main_f32<<<grid, block, 0, stream>>>(x, col_id, rn, beta, out, n);
    }
}

// Round 7
// 40.075 us; speedup vs baseline: 1.1095x; 1.0628x over previous
//
#include <hip/hip_runtime.h>
#include <math.h>
#include <stdint.h>

#define DEG 16
#define FDIM 128
#define EPSV 1e-12f

#if __has_builtin(__builtin_amdgcn_udot4)
#define UDOT4(a, b, c) __builtin_amdgcn_udot4((a), (b), (c), false)
#else
__device__ __forceinline__ uint32_t UDOT4(uint32_t a, uint32_t b, uint32_t c) {
    return c + (a & 255u) * (b & 255u) + ((a >> 8) & 255u) * ((b >> 8) & 255u)
             + ((a >> 16) & 255u) * ((b >> 16) & 255u) + (a >> 24) * (b >> 24);
}
#endif

// Prep: one wave per row. Computes rn = rsqrt(|x|^2+eps), rowmax, biased-u8
// quantized row (RNE), row byte-sum U. prm[row] = (s, s*rn, U, 0).
__global__ void agnn_prep_u8(const float* __restrict__ x,
                             uint32_t* __restrict__ xq,
                             float4* __restrict__ prm, int n) {
    int row  = (blockIdx.x * blockDim.x + threadIdx.x) >> 6;
    int lane = threadIdx.x & 63;
    if (row >= n) return;
    const float2 v = *reinterpret_cast<const float2*>(x + (size_t)row * FDIM + lane * 2);
    float s2 = v.x * v.x + v.y * v.y;
    float am = fmaxf(fabsf(v.x), fabsf(v.y));
#pragma unroll
    for (int off = 32; off >= 1; off >>= 1) {
        s2 += __shfl_xor(s2, off);
        am = fmaxf(am, __shfl_xor(am, off));
    }
    const float rn = rsqrtf(s2 + EPSV);
    const float amc = fmaxf(am, 1e-20f);
    const float is  = 127.f / amc;
    const float s   = amc * (1.f / 127.f);
    const int u0 = (int)rintf(v.x * is) + 128;   // in [1,255]
    const int u1 = (int)rintf(v.y * is) + 128;
    int us = u0 + u1;
#pragma unroll
    for (int off = 32; off >= 1; off >>= 1) us += __shfl_xor(us, off);
    reinterpret_cast<uint16_t*>(xq)[(size_t)row * 64 + lane] =
        (uint16_t)(u0 | (u1 << 8));
    if (lane == 0) prm[row] = make_float4(s, s * rn, (float)us, 0.f);
}

// Main v7: one wave per node, 4 groups x 16 lanes; group g owns neighbors
// 4g..4g+3, lane t owns dims [8t,8t+8) = 8 bytes of the u8 row. Rows are
// 128B (half of f16) -> halves the per-XCD L2 fill volume (the round-3..6
// wall). Dots are EXACT integer (v_dot4_u32_u8 + bias correction via U).
__global__ __launch_bounds__(256, 8)
void agnn_main_v7(const uint32_t* __restrict__ xq,
                  const int* __restrict__ col_id,
                  const float4* __restrict__ prm,
                  const float* __restrict__ beta,
                  float* __restrict__ out, int n) {
    int node = (blockIdx.x * blockDim.x + threadIdx.x) >> 6;
    int lane = threadIdx.x & 63;
    if (node >= n) return;
    const int g = lane >> 4;
    const int t = lane & 15;

    // issue all loads up front
    const int4  c4 = *reinterpret_cast<const int4*>(col_id + node * DEG + 4 * g);
    const uint2 xi = *reinterpret_cast<const uint2*>(xq + (size_t)node * 32 + t * 2);
    const float4 pi = prm[node];
    const float b = beta[0];

    const uint2 r0 = *reinterpret_cast<const uint2*>(xq + (size_t)c4.x * 32 + t * 2);
    const uint2 r1 = *reinterpret_cast<const uint2*>(xq + (size_t)c4.y * 32 + t * 2);
    const uint2 r2 = *reinterpret_cast<const uint2*>(xq + (size_t)c4.z * 32 + t * 2);
    const uint2 r3 = *reinterpret_cast<const uint2*>(xq + (size_t)c4.w * 32 + t * 2);
    const float4 p0 = prm[c4.x];
    const float4 p1 = prm[c4.y];
    const float4 p2 = prm[c4.z];
    const float4 p3 = prm[c4.w];

    // exact integer partial dots (8 dims per lane)
    int d0 = (int)UDOT4(r0.x, xi.x, UDOT4(r0.y, xi.y, 0u));
    int d1 = (int)UDOT4(r1.x, xi.x, UDOT4(r1.y, xi.y, 0u));
    int d2 = (int)UDOT4(r2.x, xi.x, UDOT4(r2.y, xi.y, 0u));
    int d3 = (int)UDOT4(r3.x, xi.x, UDOT4(r3.y, xi.y, 0u));

    // intra-group (16-lane) butterfly, exact int adds
#pragma unroll
    for (int off = 1; off < 16; off <<= 1) {
        d0 += __shfl_xor(d0, off);
        d1 += __shfl_xor(d1, off);
        d2 += __shfl_xor(d2, off);
        d3 += __shfl_xor(d3, off);
    }

    // bias correction: x_i . x_j = s_i s_j (D - 128(U_i+U_j) + 128*128*128)
    const float Ui = pi.z;
    const float bt = b * pi.y;                 // beta * s_i * rn_i
    float e0 = bt * p0.y * ((float)d0 - 128.f * (Ui + p0.z) + 2097152.f);
    float e1 = bt * p1.y * ((float)d1 - 128.f * (Ui + p1.z) + 2097152.f);
    float e2 = bt * p2.y * ((float)d2 - 128.f * (Ui + p2.z) + 2097152.f);
    float e3 = bt * p3.y * ((float)d3 - 128.f * (Ui + p3.z) + 2097152.f);

    // softmax (no max-sub: |e| <= |beta|, validated r5/r6)
    float w0 = __expf(e0), w1 = __expf(e1), w2 = __expf(e2), w3 = __expf(e3);
    float sum = (w0 + w1) + (w2 + w3);
    sum += __shfl_xor(sum, 16);
    sum += __shfl_xor(sum, 32);
    const float inv = 1.f / sum;
    w0 *= inv * p0.x;                          // alpha_r * s_r
    w1 *= inv * p1.x;
    w2 *= inv * p2.x;
    w3 *= inv * p3.x;
    const float cg = (w0 + w1) + (w2 + w3);    // for the -128 bias fold

    // aggregation: acc[d] = sum_r w_r * u_r[d]  (v_cvt_f32_ubyte idiom),
    // then acc[d] -= 128 * cg
    float acc[8];
#pragma unroll
    for (int k = 0; k < 4; ++k) {
        const float f0 = (float)((r0.x >> (8 * k)) & 255u);
        const float f1 = (float)((r1.x >> (8 * k)) & 255u);
        const float f2 = (float)((r2.x >> (8 * k)) & 255u);
        const float f3 = (float)((r3.x >> (8 * k)) & 255u);
        acc[k] = fmaf(w3, f3, fmaf(w2, f2, fmaf(w1, f1, w0 * f0)));
    }
#pragma unroll
    for (int k = 0; k < 4; ++k) {
        const float f0 = (float)((r0.y >> (8 * k)) & 255u);
        const float f1 = (float)((r1.y >> (8 * k)) & 255u);
        const float f2 = (float)((r2.y >> (8 * k)) & 255u);
        const float f3 = (float)((r3.y >> (8 * k)) & 255u);
        acc[4 + k] = fmaf(w3, f3, fmaf(w2, f2, fmaf(w1, f1, w0 * f0)));
    }
#pragma unroll
    for (int k = 0; k < 8; ++k) acc[k] = fmaf(-128.f, cg, acc[k]);

    // cross-group reduce
#pragma unroll
    for (int k = 0; k < 8; ++k) acc[k] += __shfl_xor(acc[k], 16);
#pragma unroll
    for (int k = 0; k < 8; ++k) acc[k] += __shfl_xor(acc[k], 32);

    if (g == 0) {
        float4* op = reinterpret_cast<float4*>(out + (size_t)node * FDIM + t * 8);
        op[0] = make_float4(acc[0], acc[1], acc[2], acc[3]);
        op[1] = make_float4(acc[4], acc[5], acc[6], acc[7]);
    }
}

// ---------- fp32 fallback (only if ws is somehow too small) ----------
__global__ void agnn_rnorm_kernel(const float* __restrict__ x,
                                  float* __restrict__ rn, int n) {
    int wave = (blockIdx.x * blockDim.x + threadIdx.x) >> 6;
    int lane = threadIdx.x & 63;
    if (wave >= n) return;
    const float2 v = *reinterpret_cast<const float2*>(x + (size_t)wave * FDIM + lane * 2);
    float s = v.x * v.x + v.y * v.y;
#pragma unroll
    for (int off = 32; off >= 1; off >>= 1)
        s += __shfl_xor(s, off);
    if (lane == 0) rn[wave] = rsqrtf(s + EPSV);
}

__global__ void agnn_main_f32(const float* __restrict__ x,
                              const int* __restrict__ col_id,
                              const float* __restrict__ rn,
                              const float* __restrict__ beta,
                              float* __restrict__ out, int n) {
    int wave = (blockIdx.x * blockDim.x + threadIdx.x) >> 6;
    int lane = threadIdx.x & 63;
    if (wave >= n) return;
    const int node = wave;
    const float b   = beta[0];
    const float rni = rn[node];
    const float2 xi = *reinterpret_cast<const float2*>(x + (size_t)node * FDIM + lane * 2);
    int cidx = col_id[node * DEG + (lane & 15)];
    float2 xj[DEG];
    float  p[DEG];
    float  rnj[DEG];
#pragma unroll
    for (int k = 0; k < DEG; ++k) {
        int cj = __shfl(cidx, k);
        const float2 v = *reinterpret_cast<const float2*>(x + (size_t)cj * FDIM + lane * 2);
        xj[k] = v; rnj[k] = rn[cj];
        p[k] = fmaf(xi.x, v.x, xi.y * v.y);
    }
#pragma unroll
    for (int off = 32; off >= 1; off >>= 1) {
#pragma unroll
        for (int k = 0; k < DEG; ++k)
            p[k] += __shfl_xor(p[k], off);
    }
    const float brni = b * rni;
#pragma unroll
    for (int k = 0; k < DEG; ++k) p[k] *= brni * rnj[k];
    float m = p[0];
#pragma unroll
    for (int k = 1; k < DEG; ++k) m = fmaxf(m, p[k]);
    float s = 0.f;
#pragma unroll
    for (int k = 0; k < DEG; ++k) { p[k] = __expf(p[k] - m); s += p[k]; }
    const float inv = 1.0f / s;
    float2 acc = make_float2(0.f, 0.f);
#pragma unroll
    for (int k = 0; k < DEG; ++k) {
        const float a = p[k] * inv;
        acc.x = fmaf(a, xj[k].x, acc.x);
        acc.y = fmaf(a, xj[k].y, acc.y);
    }
    *reinterpret_cast<float2*>(out + (size_t)node * FDIM + lane * 2) = acc;
}

extern "C" void kernel_launch(void* const* d_in, const int* in_sizes, int n_in,
                              void* d_out, int out_size, void* d_ws, size_t ws_size,
                              hipStream_t stream) {
    const float* x      = (const float*)d_in[0];
    const int*   col_id = (const int*)d_in[3];
    const float* beta   = (const float*)d_in[4];
    float*       out    = (float*)d_out;

    const int n = in_sizes[0] / FDIM;            // 50000

    const int block = 256;                       // 4 waves / block
    const int wavesPerBlock = block / 64;
    const int grid = (n + wavesPerBlock - 1) / wavesPerBlock;

    const size_t xq_bytes = (size_t)n * FDIM;               // 6.4 MB u8 rows
    const size_t need = xq_bytes + (size_t)n * sizeof(float4);

    if (ws_size >= need) {
        uint32_t* xq  = (uint32_t*)d_ws;
        float4*   prm = (float4*)((char*)d_ws + xq_bytes);
        agnn_prep_u8<<<grid, block, 0, stream>>>(x, xq, prm, n);
        agnn_main_v7<<<grid, block, 0, stream>>>(xq, col_id, prm, beta, out, n);
    } else {
        float* rn = (float*)d_ws;
        agnn_rnorm_kernel<<<grid, block, 0, stream>>>(x, rn, n);
        agnn_main_f32<<<grid, block, 0, stream>>>(x, col_id, rn, beta, out, n);
    }
}

// Round 8
// 36.830 us; speedup vs baseline: 1.2072x; 1.0881x over previous
//
#include <hip/hip_runtime.h>
#include <math.h>
#include <stdint.h>

#define DEG 16
#define FDIM 128
#define EPSV 1e-12f

#if __has_builtin(__builtin_amdgcn_sdot4)
#define SDOT4(a, b, c) __builtin_amdgcn_sdot4((int)(a), (int)(b), (c), false)
#else
__device__ __forceinline__ int SDOT4(uint32_t a, uint32_t b, int c) {
    return c + (int)(int8_t)(a & 255u) * (int)(int8_t)(b & 255u)
             + (int)(int8_t)((a >> 8) & 255u) * (int)(int8_t)((b >> 8) & 255u)
             + (int)(int8_t)((a >> 16) & 255u) * (int)(int8_t)((b >> 16) & 255u)
             + (int)(int8_t)(a >> 24) * (int)(int8_t)(b >> 24);
}
#endif

// Prep: one wave per row. rn = rsqrt(|x|^2+eps), rowmax, SIGNED-i8 quant row.
// prm[row] = (s, s*rn)  [float2, 400KB -> L2-resident]
__global__ void agnn_prep_i8(const float* __restrict__ x,
                             uint32_t* __restrict__ xq,
                             float2* __restrict__ prm, int n) {
    int row  = (blockIdx.x * blockDim.x + threadIdx.x) >> 6;
    int lane = threadIdx.x & 63;
    if (row >= n) return;
    const float2 v = *reinterpret_cast<const float2*>(x + (size_t)row * FDIM + lane * 2);
    float s2 = v.x * v.x + v.y * v.y;
    float am = fmaxf(fabsf(v.x), fabsf(v.y));
#pragma unroll
    for (int off = 32; off >= 1; off >>= 1) {
        s2 += __shfl_xor(s2, off);
        am = fmaxf(am, __shfl_xor(am, off));
    }
    const float rn  = rsqrtf(s2 + EPSV);
    const float amc = fmaxf(am, 1e-20f);
    const float is  = 127.f / amc;
    const float s   = amc * (1.f / 127.f);
    const int q0 = (int)rintf(v.x * is);       // in [-127,127]
    const int q1 = (int)rintf(v.y * is);
    reinterpret_cast<uint16_t*>(xq)[(size_t)row * 64 + lane] =
        (uint16_t)((q0 & 0xff) | ((q1 & 0xff) << 8));
    if (lane == 0) prm[row] = make_float2(s, s * rn);
}

// Main v8: one wave per node, 4 groups x 16 lanes; group g owns neighbors
// 4g..4g+3, lane t owns dims [8t,8t+8) (8 bytes of the i8 row). Signed i8:
// exact integer dots via v_dot4_i32_i8, NO bias correction, float2 params.
__global__ __launch_bounds__(256, 8)
void agnn_main_v8(const uint32_t* __restrict__ xq,
                  const int* __restrict__ col_id,
                  const float2* __restrict__ prm,
                  const float* __restrict__ beta,
                  float* __restrict__ out, int n) {
    int node = (blockIdx.x * blockDim.x + threadIdx.x) >> 6;
    int lane = threadIdx.x & 63;
    if (node >= n) return;
    const int g = lane >> 4;
    const int t = lane & 15;

    // row gathers first (L2-miss path), params after (L2-hot)
    const int4  c4 = *reinterpret_cast<const int4*>(col_id + node * DEG + 4 * g);
    const uint2 xi = *reinterpret_cast<const uint2*>(xq + (size_t)node * 32 + t * 2);
    const uint2 r0 = *reinterpret_cast<const uint2*>(xq + (size_t)c4.x * 32 + t * 2);
    const uint2 r1 = *reinterpret_cast<const uint2*>(xq + (size_t)c4.y * 32 + t * 2);
    const uint2 r2 = *reinterpret_cast<const uint2*>(xq + (size_t)c4.z * 32 + t * 2);
    const uint2 r3 = *reinterpret_cast<const uint2*>(xq + (size_t)c4.w * 32 + t * 2);
    const float2 pi = prm[node];
    const float2 p0 = prm[c4.x];
    const float2 p1 = prm[c4.y];
    const float2 p2 = prm[c4.z];
    const float2 p3 = prm[c4.w];
    const float b = beta[0];

    // exact integer partial dots (8 dims per lane)
    int d0 = SDOT4(r0.x, xi.x, SDOT4(r0.y, xi.y, 0));
    int d1 = SDOT4(r1.x, xi.x, SDOT4(r1.y, xi.y, 0));
    int d2 = SDOT4(r2.x, xi.x, SDOT4(r2.y, xi.y, 0));
    int d3 = SDOT4(r3.x, xi.x, SDOT4(r3.y, xi.y, 0));

    // intra-group (16-lane) butterfly, exact int adds
#pragma unroll
    for (int off = 1; off < 16; off <<= 1) {
        d0 += __shfl_xor(d0, off);
        d1 += __shfl_xor(d1, off);
        d2 += __shfl_xor(d2, off);
        d3 += __shfl_xor(d3, off);
    }

    // e_r = beta * (s_i rn_i) * (s_j rn_j) * D_r  -- no bias terms
    const float bt = b * pi.y;
    float w0 = __expf(bt * p0.y * (float)d0);
    float w1 = __expf(bt * p1.y * (float)d1);
    float w2 = __expf(bt * p2.y * (float)d2);
    float w3 = __expf(bt * p3.y * (float)d3);

    float sum = (w0 + w1) + (w2 + w3);
    sum += __shfl_xor(sum, 16);
    sum += __shfl_xor(sum, 32);
    const float inv = 1.f / sum;
    w0 *= inv * p0.x;                          // alpha_r * s_r
    w1 *= inv * p1.x;
    w2 *= inv * p2.x;
    w3 *= inv * p3.x;

    // aggregation: acc[d] = sum_r w_r * i8_r[d]  (signed unpack, no bias fold)
    float acc[8];
#pragma unroll
    for (int k = 0; k < 4; ++k) {
        const float f0 = (float)(int)(int8_t)((r0.x >> (8 * k)) & 255u);
        const float f1 = (float)(int)(int8_t)((r1.x >> (8 * k)) & 255u);
        const float f2 = (float)(int)(int8_t)((r2.x >> (8 * k)) & 255u);
        const float f3 = (float)(int)(int8_t)((r3.x >> (8 * k)) & 255u);
        acc[k] = fmaf(w3, f3, fmaf(w2, f2, fmaf(w1, f1, w0 * f0)));
    }
#pragma unroll
    for (int k = 0; k < 4; ++k) {
        const float f0 = (float)(int)(int8_t)((r0.y >> (8 * k)) & 255u);
        const float f1 = (float)(int)(int8_t)((r1.y >> (8 * k)) & 255u);
        const float f2 = (float)(int)(int8_t)((r2.y >> (8 * k)) & 255u);
        const float f3 = (float)(int)(int8_t)((r3.y >> (8 * k)) & 255u);
        acc[4 + k] = fmaf(w3, f3, fmaf(w2, f2, fmaf(w1, f1, w0 * f0)));
    }

    // cross-group reduce
#pragma unroll
    for (int k = 0; k < 8; ++k) acc[k] += __shfl_xor(acc[k], 16);
#pragma unroll
    for (int k = 0; k < 8; ++k) acc[k] += __shfl_xor(acc[k], 32);

    if (g == 0) {
        float4* op = reinterpret_cast<float4*>(out + (size_t)node * FDIM + t * 8);
        op[0] = make_float4(acc[0], acc[1], acc[2], acc[3]);
        op[1] = make_float4(acc[4], acc[5], acc[6], acc[7]);
    }
}

// ---------- fp32 fallback (only if ws is somehow too small) ----------
__global__ void agnn_rnorm_kernel(const float* __restrict__ x,
                                  float* __restrict__ rn, int n) {
    int wave = (blockIdx.x * blockDim.x + threadIdx.x) >> 6;
    int lane = threadIdx.x & 63;
    if (wave >= n) return;
    const float2 v = *reinterpret_cast<const float2*>(x + (size_t)wave * FDIM + lane * 2);
    float s = v.x * v.x + v.y * v.y;
#pragma unroll
    for (int off = 32; off >= 1; off >>= 1)
        s += __shfl_xor(s, off);
    if (lane == 0) rn[wave] = rsqrtf(s + EPSV);
}

__global__ void agnn_main_f32(const float* __restrict__ x,
                              const int* __restrict__ col_id,
                              const float* __restrict__ rn,
                              const float* __restrict__ beta,
                              float* __restrict__ out, int n) {
    int wave = (blockIdx.x * blockDim.x + threadIdx.x) >> 6;
    int lane = threadIdx.x & 63;
    if (wave >= n) return;
    const int node = wave;
    const float b   = beta[0];
    const float rni = rn[node];
    const float2 xi = *reinterpret_cast<const float2*>(x + (size_t)node * FDIM + lane * 2);
    int cidx = col_id[node * DEG + (lane & 15)];
    float2 xj[DEG];
    float  p[DEG];
    float  rnj[DEG];
#pragma unroll
    for (int k = 0; k < DEG; ++k) {
        int cj = __shfl(cidx, k);
        const float2 v = *reinterpret_cast<const float2*>(x + (size_t)cj * FDIM + lane * 2);
        xj[k] = v; rnj[k] = rn[cj];
        p[k] = fmaf(xi.x, v.x, xi.y * v.y);
    }
#pragma unroll
    for (int off = 32; off >= 1; off >>= 1) {
#pragma unroll
        for (int k = 0; k < DEG; ++k)
            p[k] += __shfl_xor(p[k], off);
    }
    const float brni = b * rni;
#pragma unroll
    for (int k = 0; k < DEG; ++k) p[k] *= brni * rnj[k];
    float m = p[0];
#pragma unroll
    for (int k = 1; k < DEG; ++k) m = fmaxf(m, p[k]);
    float s = 0.f;
#pragma unroll
    for (int k = 0; k < DEG; ++k) { p[k] = __expf(p[k] - m); s += p[k]; }
    const float inv = 1.0f / s;
    float2 acc = make_float2(0.f, 0.f);
#pragma unroll
    for (int k = 0; k < DEG; ++k) {
        const float a = p[k] * inv;
        acc.x = fmaf(a, xj[k].x, acc.x);
        acc.y = fmaf(a, xj[k].y, acc.y);
    }
    *reinterpret_cast<float2*>(out + (size_t)node * FDIM + lane * 2) = acc;
}

extern "C" void kernel_launch(void* const* d_in, const int* in_sizes, int n_in,
                              void* d_out, int out_size, void* d_ws, size_t ws_size,
                              hipStream_t stream) {
    const float* x      = (const float*)d_in[0];
    const int*   col_id = (const int*)d_in[3];
    const float* beta   = (const float*)d_in[4];
    float*       out    = (float*)d_out;

    const int n = in_sizes[0] / FDIM;            // 50000

    const int block = 256;                       // 4 waves / block
    const int wavesPerBlock = block / 64;
    const int grid = (n + wavesPerBlock - 1) / wavesPerBlock;

    const size_t xq_bytes = (size_t)n * FDIM;               // 6.4 MB i8 rows
    const size_t need = xq_bytes + (size_t)n * sizeof(float2);

    if (ws_size >= need) {
        uint32_t* xq  = (uint32_t*)d_ws;
        float2*   prm = (float2*)((char*)d_ws + xq_bytes);
        agnn_prep_i8<<<grid, block, 0, stream>>>(x, xq, prm, n);
        agnn_main_v8<<<grid, block, 0, stream>>>(xq, col_id, prm, beta, out, n);
    } else {
        float* rn = (float*)d_ws;
        agnn_rnorm_kernel<<<grid, block, 0, stream>>>(x, rn, n);
        agnn_main_f32<<<grid, block, 0, stream>>>(x, col_id, rn, beta, out, n);
    }
}